// Round 2
// baseline (367.608 us; speedup 1.0000x reference)
//
#include <hip/hip_runtime.h>
#include <hip/hip_bf16.h>

#define BQ_TOTAL 1024      // B*Q = 16*64
#define KLEN 1024
#define DDIM 256
#define HDIM 128

// Projection: out[r, h] = sum_d in[r,d] * W[d,h]; all fp32.
// Block = 256 threads: 8 rows x 32 threads, each thread does 4 consecutive h.
__global__ __launch_bounds__(256) void proj_kernel(
    const float* __restrict__ in,   // [rows, 256] fp32
    const float* __restrict__ W,    // [256, 128] fp32
    float* __restrict__ out,        // [rows, 128] fp32
    int rows)
{
    int tid = threadIdx.x;
    int rl  = tid >> 5;            // 0..7
    int h4  = (tid & 31) << 2;     // 0,4,...,124
    int r   = blockIdx.x * 8 + rl;
    if (r >= rows) return;

    const float* row = in + (size_t)r * DDIM;
    float a0 = 0.f, a1 = 0.f, a2 = 0.f, a3 = 0.f;

    for (int d = 0; d < DDIM; d += 4) {
        float4 rp = *(const float4*)(row + d);
        const float* wp = W + (size_t)d * HDIM + h4;
        float4 w0 = *(const float4*)(wp);
        float4 w1 = *(const float4*)(wp + HDIM);
        float4 w2 = *(const float4*)(wp + 2 * HDIM);
        float4 w3 = *(const float4*)(wp + 3 * HDIM);
        a0 = fmaf(rp.x, w0.x, a0); a0 = fmaf(rp.y, w1.x, a0);
        a0 = fmaf(rp.z, w2.x, a0); a0 = fmaf(rp.w, w3.x, a0);
        a1 = fmaf(rp.x, w0.y, a1); a1 = fmaf(rp.y, w1.y, a1);
        a1 = fmaf(rp.z, w2.y, a1); a1 = fmaf(rp.w, w3.y, a1);
        a2 = fmaf(rp.x, w0.z, a2); a2 = fmaf(rp.y, w1.z, a2);
        a2 = fmaf(rp.z, w2.z, a2); a2 = fmaf(rp.w, w3.z, a2);
        a3 = fmaf(rp.x, w0.w, a3); a3 = fmaf(rp.y, w1.w, a3);
        a3 = fmaf(rp.z, w2.w, a3); a3 = fmaf(rp.w, w3.w, a3);
    }
    *(float4*)(out + (size_t)r * HDIM + h4) = make_float4(a0, a1, a2, a3);
}

// Fused scores + masked softmax + attn@V. One block per (b,q), 256 threads.
__global__ __launch_bounds__(256) void attn_kernel(
    const float* __restrict__ q_proj,      // [B*Q, 128] fp32
    const float* __restrict__ k_proj,      // [B*K, 128] fp32
    const float* __restrict__ values,      // [B, K, 256] fp32
    const int* __restrict__ valid_lens,    // [B]
    const float* __restrict__ w_v,         // [128] fp32
    float* __restrict__ out)               // [B, Q, 256] fp32
{
    __shared__ float s_lds[KLEN];
    __shared__ float qp_lds[HDIM];
    __shared__ float wv_lds[HDIM];
    __shared__ float red[8];

    int tid = threadIdx.x;
    int bq  = blockIdx.x;
    int b   = bq >> 6;
    int vlen = valid_lens[b];

    if (tid < HDIM) {
        qp_lds[tid] = q_proj[(size_t)bq * HDIM + tid];
        wv_lds[tid] = w_v[tid];
    }
    __syncthreads();

    int wave = tid >> 6, lane = tid & 63;
    float qv0 = qp_lds[lane], qv1 = qp_lds[lane + 64];
    float wv0 = wv_lds[lane], wv1 = wv_lds[lane + 64];
    const float* kpb = k_proj + (size_t)b * KLEN * HDIM;

    // Phase 1: scores. Each wave owns one k at a time; 64 lanes cover h=lane, lane+64.
    for (int k = wave; k < vlen; k += 4) {
        const float* kp = kpb + (size_t)k * HDIM;
        float x0 = qv0 + kp[lane];
        float x1 = qv1 + kp[lane + 64];
        // tanh(x) = 1 - 2/(exp(2x)+1); exact saturation at +/-inf
        float t0 = 1.0f - 2.0f / (__expf(2.0f * x0) + 1.0f);
        float t1 = 1.0f - 2.0f / (__expf(2.0f * x1) + 1.0f);
        float v = wv0 * t0 + wv1 * t1;
        #pragma unroll
        for (int off = 32; off > 0; off >>= 1) v += __shfl_xor(v, off, 64);
        if (lane == 0) s_lds[k] = v;
    }
    __syncthreads();

    // Phase 2: masked softmax over k < vlen (masked slots get exactly 0 weight).
    float m = -1e30f;
    for (int i = tid; i < vlen; i += 256) m = fmaxf(m, s_lds[i]);
    #pragma unroll
    for (int off = 32; off > 0; off >>= 1) m = fmaxf(m, __shfl_xor(m, off, 64));
    if (lane == 0) red[wave] = m;
    __syncthreads();
    m = fmaxf(fmaxf(red[0], red[1]), fmaxf(red[2], red[3]));

    float s = 0.0f;
    for (int i = tid; i < vlen; i += 256) {
        float e = __expf(s_lds[i] - m);
        s_lds[i] = e;
        s += e;
    }
    #pragma unroll
    for (int off = 32; off > 0; off >>= 1) s += __shfl_xor(s, off, 64);
    __syncthreads();   // all reads of red[] (max) complete before rewrite
    if (lane == 0) red[wave] = s;
    __syncthreads();
    float inv = 1.0f / (red[0] + red[1] + red[2] + red[3]);

    // Phase 3: out[d] = (sum_k e_k * V[b,k,d]) * inv ; thread = d, coalesced V reads.
    const float* vb = values + (size_t)b * KLEN * DDIM + tid;
    float acc = 0.0f;
    #pragma unroll 4
    for (int k = 0; k < vlen; k++) {
        acc = fmaf(s_lds[k], vb[(size_t)k * DDIM], acc);
    }
    out[(size_t)bq * DDIM + tid] = acc * inv;
}

extern "C" void kernel_launch(void* const* d_in, const int* in_sizes, int n_in,
                              void* d_out, int out_size, void* d_ws, size_t ws_size,
                              hipStream_t stream) {
    const float* queries    = (const float*)d_in[0]; // [16,64,256]
    const float* keys       = (const float*)d_in[1]; // [16,1024,256]
    const float* values     = (const float*)d_in[2]; // [16,1024,256]
    const int*   valid_lens = (const int*)d_in[3];   // [16]
    const float* W_q        = (const float*)d_in[4]; // [256,128]
    const float* W_k        = (const float*)d_in[5]; // [256,128]
    const float* w_v        = (const float*)d_in[6]; // [128]

    float* q_proj = (float*)d_ws;                      // 1024*128 fp32
    float* k_proj = q_proj + (size_t)BQ_TOTAL * HDIM;  // 16384*128 fp32

    // q projection: 1024 rows -> 128 blocks
    proj_kernel<<<128, 256, 0, stream>>>(queries, W_q, q_proj, BQ_TOTAL);
    // k projection: 16384 rows -> 2048 blocks
    proj_kernel<<<2048, 256, 0, stream>>>(keys, W_k, k_proj, 16 * KLEN);
    // fused attention: one block per (b,q)
    attn_kernel<<<BQ_TOTAL, 256, 0, stream>>>(q_proj, k_proj, values, valid_lens, w_v,
                                              (float*)d_out);
}

// Round 3
// 188.495 us; speedup vs baseline: 1.9502x; 1.9502x over previous
//
#include <hip/hip_runtime.h>
#include <hip/hip_bf16.h>

#define DDIM 256
#define HDIM 128
#define KLEN 1024
#define KH   512      // k-half per attn block (split-K factor 2)

// ---------------- Projection: out[r,h] = sum_d in[r,d] * W[d,h] ----------------
// Block = 32 rows x 128 h. 256 threads: thread = (rg 0..7, hg 0..31) -> 4 rows x 4 h accs.
// W d-tile (64x128 = 32 KB) staged in LDS; input rows read as L1-broadcast float4.
__global__ __launch_bounds__(256) void proj_kernel(
    const float* __restrict__ queries, const float* __restrict__ keys,
    const float* __restrict__ W_q, const float* __restrict__ W_k,
    float* __restrict__ q_proj, float* __restrict__ k_proj)
{
    __shared__ float Wt[64][HDIM];   // 32 KB

    int blk = blockIdx.x;
    const float* in; const float* W; float* out; int row0;
    if (blk < 512) { in = keys;    W = W_k; out = k_proj; row0 = blk * 32; }
    else           { in = queries; W = W_q; out = q_proj; row0 = (blk - 512) * 32; }

    int tid = threadIdx.x;
    int hg = tid & 31;   int h0 = hg << 2;   // 4 consecutive h
    int rg = tid >> 5;   int r0 = rg << 2;   // 4 consecutive rows

    float4 acc[4];
    #pragma unroll
    for (int j = 0; j < 4; j++) acc[j] = make_float4(0.f, 0.f, 0.f, 0.f);

    for (int dt = 0; dt < DDIM; dt += 64) {
        __syncthreads();
        // stage W[dt..dt+63][0..127] -> Wt (flat, coalesced, b128 aligned)
        const float4* Wg = (const float4*)(W + (size_t)dt * HDIM);
        float4* Wl = (float4*)(&Wt[0][0]);
        #pragma unroll
        for (int i = 0; i < 8; i++) Wl[tid + 256 * i] = Wg[tid + 256 * i];
        __syncthreads();

        #pragma unroll 4
        for (int d4 = 0; d4 < 64; d4 += 4) {
            float4 wv4[4];
            #pragma unroll
            for (int dd = 0; dd < 4; dd++)
                wv4[dd] = *(const float4*)(&Wt[d4 + dd][h0]);
            #pragma unroll
            for (int j = 0; j < 4; j++) {
                float4 a = *(const float4*)(in + (size_t)(row0 + r0 + j) * DDIM + dt + d4);
                acc[j].x = fmaf(a.x, wv4[0].x, acc[j].x);
                acc[j].y = fmaf(a.x, wv4[0].y, acc[j].y);
                acc[j].z = fmaf(a.x, wv4[0].z, acc[j].z);
                acc[j].w = fmaf(a.x, wv4[0].w, acc[j].w);
                acc[j].x = fmaf(a.y, wv4[1].x, acc[j].x);
                acc[j].y = fmaf(a.y, wv4[1].y, acc[j].y);
                acc[j].z = fmaf(a.y, wv4[1].z, acc[j].z);
                acc[j].w = fmaf(a.y, wv4[1].w, acc[j].w);
                acc[j].x = fmaf(a.z, wv4[2].x, acc[j].x);
                acc[j].y = fmaf(a.z, wv4[2].y, acc[j].y);
                acc[j].z = fmaf(a.z, wv4[2].z, acc[j].z);
                acc[j].w = fmaf(a.z, wv4[2].w, acc[j].w);
                acc[j].x = fmaf(a.w, wv4[3].x, acc[j].x);
                acc[j].y = fmaf(a.w, wv4[3].y, acc[j].y);
                acc[j].z = fmaf(a.w, wv4[3].z, acc[j].z);
                acc[j].w = fmaf(a.w, wv4[3].w, acc[j].w);
            }
        }
    }
    #pragma unroll
    for (int j = 0; j < 4; j++)
        *(float4*)(out + (size_t)(row0 + r0 + j) * HDIM + h0) = acc[j];
}

// ---------------- Fused attention over one k-half ----------------
// Block = (b, 4-q tile, k-half). 256 threads, 4 waves. wave = q, lane = k-in-tile.
// Emits unnormalized partial output + (m, s) stats per q for flash-style combine.
__global__ __launch_bounds__(256) void attn_kernel(
    const float* __restrict__ q_proj,      // [1024,128]
    const float* __restrict__ k_proj,      // [16384,128]
    const float* __restrict__ values,      // [16,1024,256]
    const int* __restrict__ valid_lens,    // [16]
    const float* __restrict__ w_v,         // [128]
    float* __restrict__ part_out,          // [512][4][256]
    float* __restrict__ part_stats)        // [512][4][2]
{
    __shared__ float ktile[64][132];   // 33.8 KB, pad 128->132: b128 start bank = (4k+h)%32
    __shared__ float sc[KH][4];        // 8 KB, k-major q-minor -> one b128 broadcast in AV
    __shared__ float qp[4][HDIM];      // 2 KB
    __shared__ float wvl[HDIM];        // 0.5 KB

    int tid = threadIdx.x, wave = tid >> 6, lane = tid & 63;
    int blk = blockIdx.x;
    int b  = blk >> 5;
    int qt = (blk >> 1) & 15;
    int jh = blk & 1;
    int vlen = valid_lens[b];
    int kbeg = jh * KH;
    int kcount = vlen - kbeg;
    kcount = kcount < 0 ? 0 : (kcount > KH ? KH : kcount);

    int bq0 = b * 64 + qt * 4;
    for (int i = tid; i < 4 * HDIM; i += 256)
        ((float*)qp)[i] = q_proj[(size_t)bq0 * HDIM + i];
    if (tid < HDIM) wvl[tid] = w_v[tid];

    // ---- Phase 1: scores for this k-half ----
    const float* kpb = k_proj + ((size_t)b * KLEN + kbeg) * HDIM;
    int ntile = (kcount + 63) >> 6;
    for (int t = 0; t < ntile; t++) {
        __syncthreads();   // also covers qp/wvl init on t==0
        const float4* src = (const float4*)(kpb + (size_t)t * 64 * HDIM);
        #pragma unroll
        for (int i = 0; i < 8; i++) {
            int idx = tid + 256 * i;                 // 2048 float4s = 64 rows
            int r = idx >> 5, c = (idx & 31) << 2;
            *(float4*)(&ktile[r][c]) = src[idx];
        }
        __syncthreads();

        int kl = (t << 6) + lane;
        if (kl < kcount) {
            const float* krow = &ktile[lane][0];
            const float* qrow = &qp[wave][0];
            float4 acc = make_float4(0.f, 0.f, 0.f, 0.f);
            #pragma unroll 8
            for (int h = 0; h < HDIM; h += 4) {
                float4 kk = *(const float4*)(krow + h);
                float4 qq = *(const float4*)(qrow + h);
                float4 ww = *(const float4*)(&wvl[h]);
                float x0 = qq.x + kk.x;
                float x1 = qq.y + kk.y;
                float x2 = qq.z + kk.z;
                float x3 = qq.w + kk.w;
                float r0 = __builtin_amdgcn_rcpf(__expf(x0 + x0) + 1.0f);
                float r1 = __builtin_amdgcn_rcpf(__expf(x1 + x1) + 1.0f);
                float r2 = __builtin_amdgcn_rcpf(__expf(x2 + x2) + 1.0f);
                float r3 = __builtin_amdgcn_rcpf(__expf(x3 + x3) + 1.0f);
                acc.x = fmaf(ww.x, r0, acc.x);
                acc.y = fmaf(ww.y, r1, acc.y);
                acc.z = fmaf(ww.z, r2, acc.z);
                acc.w = fmaf(ww.w, r3, acc.w);
            }
            // softmax shift-invariance: score = const - 2*acc -> use -2*acc
            sc[kl][wave] = -2.0f * (acc.x + acc.y + acc.z + acc.w);
        } else if (kl < KH) {
            sc[kl][wave] = -1e30f;
        }
    }
    __syncthreads();

    // ---- Phase 2: per-q softmax stats over this half (wave w handles q=w) ----
    float m = -1e30f;
    for (int i = lane; i < kcount; i += 64) m = fmaxf(m, sc[i][wave]);
    #pragma unroll
    for (int off = 32; off > 0; off >>= 1) m = fmaxf(m, __shfl_xor(m, off, 64));
    float s = 0.f;
    for (int i = lane; i < kcount; i += 64) {
        float e = __expf(sc[i][wave] - m);
        sc[i][wave] = e;
        s += e;
    }
    #pragma unroll
    for (int off = 32; off > 0; off >>= 1) s += __shfl_xor(s, off, 64);
    if (lane == 0) {
        part_stats[(size_t)blk * 8 + wave * 2 + 0] = m;
        part_stats[(size_t)blk * 8 + wave * 2 + 1] = s;
    }
    __syncthreads();

    // ---- Phase 3: partial AV. thread = d; one V read serves all 4 q. ----
    const float* vb = values + ((size_t)b * KLEN + kbeg) * DDIM + tid;
    float4 oacc = make_float4(0.f, 0.f, 0.f, 0.f);
    #pragma unroll 4
    for (int k = 0; k < kcount; k++) {
        float v = vb[(size_t)k * DDIM];
        float4 p = *(const float4*)(&sc[k][0]);
        oacc.x = fmaf(p.x, v, oacc.x);
        oacc.y = fmaf(p.y, v, oacc.y);
        oacc.z = fmaf(p.z, v, oacc.z);
        oacc.w = fmaf(p.w, v, oacc.w);
    }
    float* po = part_out + (size_t)blk * 4 * DDIM;
    po[0 * DDIM + tid] = oacc.x;
    po[1 * DDIM + tid] = oacc.y;
    po[2 * DDIM + tid] = oacc.z;
    po[3 * DDIM + tid] = oacc.w;
}

// ---------------- Combine the two k-halves (flash-style merge) ----------------
__global__ __launch_bounds__(256) void combine_kernel(
    const float* __restrict__ part_out, const float* __restrict__ part_stats,
    float* __restrict__ out)
{
    int bq = blockIdx.x;           // 0..1023
    int t  = threadIdx.x;
    int b = bq >> 6, q = bq & 63;
    int qt = q >> 2, qi = q & 3;
    int blk0 = b * 32 + qt * 2;

    float m0 = part_stats[(size_t)blk0 * 8 + qi * 2 + 0];
    float s0 = part_stats[(size_t)blk0 * 8 + qi * 2 + 1];
    float m1 = part_stats[(size_t)(blk0 + 1) * 8 + qi * 2 + 0];
    float s1 = part_stats[(size_t)(blk0 + 1) * 8 + qi * 2 + 1];
    float m  = fmaxf(m0, m1);
    float a0 = __expf(m0 - m), a1 = __expf(m1 - m);
    float inv = 1.0f / (s0 * a0 + s1 * a1);

    float v0 = part_out[((size_t)blk0 * 4 + qi) * DDIM + t];
    float v1 = part_out[((size_t)(blk0 + 1) * 4 + qi) * DDIM + t];
    out[(size_t)bq * DDIM + t] = (a0 * v0 + a1 * v1) * inv;
}

extern "C" void kernel_launch(void* const* d_in, const int* in_sizes, int n_in,
                              void* d_out, int out_size, void* d_ws, size_t ws_size,
                              hipStream_t stream) {
    const float* queries    = (const float*)d_in[0]; // [16,64,256]
    const float* keys       = (const float*)d_in[1]; // [16,1024,256]
    const float* values     = (const float*)d_in[2]; // [16,1024,256]
    const int*   valid_lens = (const int*)d_in[3];   // [16]
    const float* W_q        = (const float*)d_in[4]; // [256,128]
    const float* W_k        = (const float*)d_in[5]; // [256,128]
    const float* w_v        = (const float*)d_in[6]; // [128]

    float* q_proj     = (float*)d_ws;                          // 1024*128   = 512 KB
    float* k_proj     = q_proj + (size_t)1024 * HDIM;          // 16384*128  = 8 MB
    float* part_out   = k_proj + (size_t)16384 * HDIM;         // 512*4*256  = 2 MB
    float* part_stats = part_out + (size_t)512 * 4 * DDIM;     // 512*8      = 16 KB

    // fused q+k projection: 512 key-blocks + 32 query-blocks
    proj_kernel<<<544, 256, 0, stream>>>(queries, keys, W_q, W_k, q_proj, k_proj);
    // attention partials: (16 b) x (16 q-tiles) x (2 k-halves) = 512 blocks
    attn_kernel<<<512, 256, 0, stream>>>(q_proj, k_proj, values, valid_lens, w_v,
                                         part_out, part_stats);
    // merge halves
    combine_kernel<<<1024, 256, 0, stream>>>(part_out, part_stats, (float*)d_out);
}

// Round 4
// 177.152 us; speedup vs baseline: 2.0751x; 1.0640x over previous
//
#include <hip/hip_runtime.h>

#define DDIM 256
#define HDIM 128
#define KLEN 1024

// ============ Projection + transpose ============
// out = 2 * (in @ W).  Blocks 0..255: keys -> k2T[b][h][k] (h-major, transposed).
// Blocks 256..271: queries -> q2[bq][h] (row-major).
// 64 rows/block, 256 threads: thread = (rg 0..7 -> 8 rows, hg 0..31 -> 4 h).
__global__ __launch_bounds__(256) void proj_kernel(
    const float* __restrict__ queries, const float* __restrict__ keys,
    const float* __restrict__ W_q, const float* __restrict__ W_k,
    float* __restrict__ q2, float* __restrict__ k2T)
{
    __shared__ float Wt[64][HDIM];   // 32 KB; reused as transpose staging afterwards
    int blk = blockIdx.x;
    bool iskey = blk < 256;
    const float* in = iskey ? keys : queries;
    const float* W  = iskey ? W_k : W_q;
    int row0 = (iskey ? blk : blk - 256) * 64;

    int tid = threadIdx.x;
    int hg = tid & 31, h0 = hg << 2;
    int rg = tid >> 5;

    float4 acc[8];
    #pragma unroll
    for (int j = 0; j < 8; j++) acc[j] = make_float4(0.f, 0.f, 0.f, 0.f);

    for (int dt = 0; dt < DDIM; dt += 64) {
        __syncthreads();
        const float4* Wg = (const float4*)(W + (size_t)dt * HDIM);
        float4* Wl = (float4*)(&Wt[0][0]);
        #pragma unroll
        for (int i = 0; i < 8; i++) Wl[tid + 256 * i] = Wg[tid + 256 * i];
        __syncthreads();

        #pragma unroll 2
        for (int d4 = 0; d4 < 64; d4 += 4) {
            float4 wr[4];
            #pragma unroll
            for (int dd = 0; dd < 4; dd++)
                wr[dd] = *(const float4*)(&Wt[d4 + dd][h0]);
            #pragma unroll
            for (int j = 0; j < 8; j++) {
                float4 a = *(const float4*)(in + (size_t)(row0 + rg * 8 + j) * DDIM + dt + d4);
                acc[j].x = fmaf(a.x, wr[0].x, acc[j].x);
                acc[j].y = fmaf(a.x, wr[0].y, acc[j].y);
                acc[j].z = fmaf(a.x, wr[0].z, acc[j].z);
                acc[j].w = fmaf(a.x, wr[0].w, acc[j].w);
                acc[j].x = fmaf(a.y, wr[1].x, acc[j].x);
                acc[j].y = fmaf(a.y, wr[1].y, acc[j].y);
                acc[j].z = fmaf(a.y, wr[1].z, acc[j].z);
                acc[j].w = fmaf(a.y, wr[1].w, acc[j].w);
                acc[j].x = fmaf(a.z, wr[2].x, acc[j].x);
                acc[j].y = fmaf(a.z, wr[2].y, acc[j].y);
                acc[j].z = fmaf(a.z, wr[2].z, acc[j].z);
                acc[j].w = fmaf(a.z, wr[2].w, acc[j].w);
                acc[j].x = fmaf(a.w, wr[3].x, acc[j].x);
                acc[j].y = fmaf(a.w, wr[3].y, acc[j].y);
                acc[j].z = fmaf(a.w, wr[3].z, acc[j].z);
                acc[j].w = fmaf(a.w, wr[3].w, acc[j].w);
            }
        }
    }
    // pre-scale by 2 (tanh arg is exp(2x); kills a mul in the score loop)
    #pragma unroll
    for (int j = 0; j < 8; j++) {
        acc[j].x *= 2.f; acc[j].y *= 2.f; acc[j].z *= 2.f; acc[j].w *= 2.f;
    }

    if (!iskey) {
        #pragma unroll
        for (int j = 0; j < 8; j++)
            *(float4*)(q2 + (size_t)(row0 + rg * 8 + j) * HDIM + h0) = acc[j];
    } else {
        // transpose through LDS (XOR swizzle breaks the 32-way write conflict)
        float* kst = &Wt[0][0];          // 8192 floats, reuse
        __syncthreads();                 // last Wt reads done
        #pragma unroll
        for (int j = 0; j < 8; j++) {
            int kl = rg * 8 + j;
            kst[(h0 + 0) * 64 + (kl ^ ((h0 + 0) & 63))] = acc[j].x;
            kst[(h0 + 1) * 64 + (kl ^ ((h0 + 1) & 63))] = acc[j].y;
            kst[(h0 + 2) * 64 + (kl ^ ((h0 + 2) & 63))] = acc[j].z;
            kst[(h0 + 3) * 64 + (kl ^ ((h0 + 3) & 63))] = acc[j].w;
        }
        __syncthreads();
        int b   = row0 >> 10;
        int kc0 = row0 & 1023;
        int h   = tid >> 1;              // 0..127
        int klb = (tid & 1) * 32;
        int hx  = h & 63;
        float* dst = k2T + (size_t)b * HDIM * KLEN + (size_t)h * KLEN + kc0 + klb;
        #pragma unroll
        for (int c = 0; c < 32; c += 4) {
            float4 o;
            o.x = kst[h * 64 + ((klb + c + 0) ^ hx)];
            o.y = kst[h * 64 + ((klb + c + 1) ^ hx)];
            o.z = kst[h * 64 + ((klb + c + 2) ^ hx)];
            o.w = kst[h * 64 + ((klb + c + 3) ^ hx)];
            *(float4*)(dst + c) = o;
        }
    }
}

// ============ Scores + masked softmax ============
// One block per (b,q). thread = k (256 at a time, 4 tiles). Inner loop:
// coalesced global k2T reads + LDS b128 broadcasts of q2/w2. Writes normalized p.
__global__ __launch_bounds__(256) void score_kernel(
    const float* __restrict__ q2, const float* __restrict__ k2T,
    const float* __restrict__ w_v, const int* __restrict__ valid_lens,
    float* __restrict__ p)
{
    __shared__ float qw[HDIM];
    __shared__ float w2[HDIM];
    __shared__ float sc[KLEN];
    __shared__ float red[8];

    int tid = threadIdx.x;
    int bq = blockIdx.x, b = bq >> 6;
    int vlen = valid_lens[b];
    if (tid < HDIM) {
        qw[tid] = q2[(size_t)bq * HDIM + tid];
        w2[tid] = -2.0f * w_v[tid];
    }
    __syncthreads();

    const float* kb = k2T + (size_t)b * HDIM * KLEN;
    int wave = tid >> 6, lane = tid & 63;

    #pragma unroll
    for (int kt = 0; kt < 4; kt++) {
        int k = kt * 256 + tid;
        float s = -1e30f;
        if (k < vlen) {
            const float* kp = kb + k;
            float a0 = 0.f;
            // score' = sum_h (-2*wv[h]) / (exp(2(q+k)) + 1)  (softmax-shift-equivalent)
            #pragma unroll 4
            for (int h = 0; h < HDIM; h += 4) {
                float4 qv  = *(const float4*)(&qw[h]);
                float4 wv4 = *(const float4*)(&w2[h]);
                float k0 = kp[(size_t)(h + 0) * KLEN];
                float k1 = kp[(size_t)(h + 1) * KLEN];
                float k2v = kp[(size_t)(h + 2) * KLEN];
                float k3 = kp[(size_t)(h + 3) * KLEN];
                float r0 = __builtin_amdgcn_rcpf(__expf(qv.x + k0) + 1.0f);
                float r1 = __builtin_amdgcn_rcpf(__expf(qv.y + k1) + 1.0f);
                float r2 = __builtin_amdgcn_rcpf(__expf(qv.z + k2v) + 1.0f);
                float r3 = __builtin_amdgcn_rcpf(__expf(qv.w + k3) + 1.0f);
                a0 = fmaf(wv4.x, r0, a0);
                a0 = fmaf(wv4.y, r1, a0);
                a0 = fmaf(wv4.z, r2, a0);
                a0 = fmaf(wv4.w, r3, a0);
            }
            s = a0;
        }
        sc[k] = s;
    }
    __syncthreads();

    float m = fmaxf(fmaxf(sc[tid], sc[tid + 256]), fmaxf(sc[tid + 512], sc[tid + 768]));
    #pragma unroll
    for (int off = 32; off > 0; off >>= 1) m = fmaxf(m, __shfl_xor(m, off, 64));
    if (lane == 0) red[wave] = m;
    __syncthreads();
    m = fmaxf(fmaxf(red[0], red[1]), fmaxf(red[2], red[3]));

    float e0 = __expf(sc[tid] - m);
    float e1 = __expf(sc[tid + 256] - m);
    float e2 = __expf(sc[tid + 512] - m);
    float e3 = __expf(sc[tid + 768] - m);
    float ssum = e0 + e1 + e2 + e3;
    #pragma unroll
    for (int off = 32; off > 0; off >>= 1) ssum += __shfl_xor(ssum, off, 64);
    if (lane == 0) red[4 + wave] = ssum;
    __syncthreads();
    float inv = 1.0f / (red[4] + red[5] + red[6] + red[7]);

    float* pr = p + (size_t)bq * KLEN;
    pr[tid]       = e0 * inv;   // k >= vlen: exp(-1e30-m)=0 -> exact 0 weight
    pr[tid + 256] = e1 * inv;
    pr[tid + 512] = e2 * inv;
    pr[tid + 768] = e3 * inv;
}

// ============ attn @ V (k-split partials) ============
// Block = (b, 4-q tile, k-half). thread = d. p via wave-uniform (scalar) loads,
// V coalesced. Always stores (zeros if kc==0) -> poison-safe.
__global__ __launch_bounds__(256) void av_kernel(
    const float* __restrict__ p, const float* __restrict__ values,
    const int* __restrict__ valid_lens, float* __restrict__ part)
{
    int blk = blockIdx.x;
    int b = blk >> 5, qt = (blk >> 1) & 15, kh = blk & 1;
    int tid = threadIdx.x;
    int vlen = valid_lens[b];
    int kbeg = kh << 9;
    int kc = vlen - kbeg; kc = kc < 0 ? 0 : (kc > 512 ? 512 : kc);
    int bq0 = b * 64 + qt * 4;

    const float* vb = values + ((size_t)b * KLEN + kbeg) * DDIM + tid;
    const float* p0 = p + (size_t)bq0 * KLEN + kbeg;
    float4 o = make_float4(0.f, 0.f, 0.f, 0.f);

    int k = 0;
    #pragma unroll 2
    for (; k + 3 < kc; k += 4) {
        float4 pa = *(const float4*)(p0 + k);
        float4 pb = *(const float4*)(p0 + KLEN + k);
        float4 pc = *(const float4*)(p0 + 2 * KLEN + k);
        float4 pd = *(const float4*)(p0 + 3 * KLEN + k);
        float v0 = vb[(size_t)(k + 0) * DDIM];
        float v1 = vb[(size_t)(k + 1) * DDIM];
        float v2 = vb[(size_t)(k + 2) * DDIM];
        float v3 = vb[(size_t)(k + 3) * DDIM];
        o.x = fmaf(pa.x, v0, o.x); o.x = fmaf(pa.y, v1, o.x);
        o.x = fmaf(pa.z, v2, o.x); o.x = fmaf(pa.w, v3, o.x);
        o.y = fmaf(pb.x, v0, o.y); o.y = fmaf(pb.y, v1, o.y);
        o.y = fmaf(pb.z, v2, o.y); o.y = fmaf(pb.w, v3, o.y);
        o.z = fmaf(pc.x, v0, o.z); o.z = fmaf(pc.y, v1, o.z);
        o.z = fmaf(pc.z, v2, o.z); o.z = fmaf(pc.w, v3, o.z);
        o.w = fmaf(pd.x, v0, o.w); o.w = fmaf(pd.y, v1, o.w);
        o.w = fmaf(pd.z, v2, o.w); o.w = fmaf(pd.w, v3, o.w);
    }
    for (; k < kc; k++) {
        float v = vb[(size_t)k * DDIM];
        o.x = fmaf(p0[k], v, o.x);
        o.y = fmaf(p0[KLEN + k], v, o.y);
        o.z = fmaf(p0[2 * KLEN + k], v, o.z);
        o.w = fmaf(p0[3 * KLEN + k], v, o.w);
    }
    float* pt = part + ((size_t)kh * 1024 + bq0) * DDIM + tid;
    pt[0]        = o.x;
    pt[DDIM]     = o.y;
    pt[2 * DDIM] = o.z;
    pt[3 * DDIM] = o.w;
}

__global__ __launch_bounds__(256) void combine_kernel(
    const float* __restrict__ part, float* __restrict__ out)
{
    size_t i = (size_t)blockIdx.x * DDIM + threadIdx.x;
    out[i] = part[i] + part[(size_t)1024 * DDIM + i];
}

extern "C" void kernel_launch(void* const* d_in, const int* in_sizes, int n_in,
                              void* d_out, int out_size, void* d_ws, size_t ws_size,
                              hipStream_t stream) {
    const float* queries    = (const float*)d_in[0]; // [16,64,256]
    const float* keys       = (const float*)d_in[1]; // [16,1024,256]
    const float* values     = (const float*)d_in[2]; // [16,1024,256]
    const int*   valid_lens = (const int*)d_in[3];   // [16]
    const float* W_q        = (const float*)d_in[4]; // [256,128]
    const float* W_k        = (const float*)d_in[5]; // [256,128]
    const float* w_v        = (const float*)d_in[6]; // [128]

    float* q2   = (float*)d_ws;            // 1024*128          = 512 KB
    float* k2T  = q2 + 131072;             // 16*128*1024       = 8 MB
    float* p    = k2T + 2097152;           // 1024*1024         = 4 MB
    float* part = k2T;                     // alias: k2T dead after score_kernel (2 MB used)

    proj_kernel<<<272, 256, 0, stream>>>(queries, keys, W_q, W_k, q2, k2T);
    score_kernel<<<1024, 256, 0, stream>>>(q2, k2T, w_v, valid_lens, p);
    av_kernel<<<512, 256, 0, stream>>>(p, values, valid_lens, part);
    combine_kernel<<<1024, 256, 0, stream>>>(part, (float*)d_out);
}